// Round 1
// 7436.431 us; speedup vs baseline: 1.3032x; 1.3032x over previous
//
#include <hip/hip_runtime.h>
#include <hip/hip_bf16.h>

#define B_ 512
#define T_ 256
#define F_ 128
#define H_ 1024
#define KD 1152          // F_ + H_
#define NBLK 256
#define HPBUF 524288     // elems per hpack buffer: 32 hseg * 512 rows * 32
#define WP_NB 147456     // elems per nb slice of packed W: 36 c32 * 8 frags * 512
#define SBUF 16384       // shorts per stage buffer: 2 kg * 2 c32 * 8 frags * 512 (32 KiB)

typedef __attribute__((ext_vector_type(8))) short short8;
typedef __attribute__((ext_vector_type(4))) float float4v;

#define MFMA(a,b,c) __builtin_amdgcn_mfma_f32_16x16x32_bf16(a,b,c,0,0,0)

__device__ __forceinline__ unsigned short f2bf(float x){
  unsigned u = __float_as_uint(x);
  unsigned r = (u + 0x7fffu + ((u >> 16) & 1u)) >> 16;
  return (unsigned short)r;
}
__device__ __forceinline__ float bf2f(unsigned short b){
  return __uint_as_float(((unsigned)b) << 16);
}
__device__ __forceinline__ float sigf(float x){ return 1.f / (1.f + __expf(-x)); }
__device__ __forceinline__ float tanh_f(float x){
  float e = __expf(2.f * x);
  return (e - 1.f) / (e + 1.f);
}

// async global->LDS copy, 16B per lane. lbase must be wave-uniform; HW adds lane*16.
__device__ __forceinline__ void cp16(const unsigned short* g, unsigned short* lbase, int lane){
#if defined(__has_builtin) && __has_builtin(__builtin_amdgcn_global_load_lds)
  __builtin_amdgcn_global_load_lds((const __attribute__((address_space(1))) unsigned int*)g,
                                   (__attribute__((address_space(3))) unsigned int*)lbase, 16, 0, 0);
#else
  *(short8*)(lbase + lane * 8) = *(const short8*)g;
#endif
}

// ---------------- W pre-pack: split hi/lo bf16 and lay out in MFMA B-fragment order -------------
// wp[nb][c32][frag 0..7][lane*8+j], frag 0..3 = hi for ntile(gate) 0..3, 4..7 = lo.
__global__ void __launch_bounds__(256) pack_w(const float* __restrict__ Wl, unsigned short* __restrict__ wp){
  int bid = blockIdx.x;                 // 64*36
  int nb = bid / 36, c32 = bid % 36;
  int tid = threadIdx.x;
  int nt = tid >> 6, lane = tid & 63;
  int u = lane & 15, q = lane >> 4;
  int gcol = nt * H_ + nb * 16 + u;     // ntile == gate
  int k0 = c32 * 32 + q * 8;
  short8 hi, lo;
#pragma unroll
  for (int j = 0; j < 8; j++){
    float x = Wl[(size_t)(k0 + j) * 4096 + gcol];
    unsigned short hb = f2bf(x);
    hi[j] = (short)hb;
    lo[j] = (short)f2bf(x - bf2f(hb));
  }
  size_t base = (size_t)(nb * 36 + c32) * 8;
  *(short8*)&wp[(base + nt) * 512 + lane * 8] = hi;
  *(short8*)&wp[(base + 4 + nt) * 512 + lane * 8] = lo;
}

// ---------------- persistent cooperative LSTM kernel ----------------
// 8 waves: wr = w&3 picks 32-row group, kg = w>>2 picks K-half.
// kg0: c32 {0,1} + h c32 4..19 ; kg1: c32 {2,3} + h c32 20..35.
// Phase p stages/computes 2 c32 per kg (32 KiB per phase, double-buffered).
__device__ __forceinline__ void stage_phase(const unsigned short* __restrict__ wpnb,
                                            unsigned short* dst, int p, int w, int lane){
#pragma unroll
  for (int i = 0; i < 4; i++){
    int idx = w * 4 + i;                 // 32 chunks of 1 KiB
    int kgs = idx >> 4, lc = (idx >> 3) & 1, frag = idx & 7;
    int c32 = (p == 0) ? (kgs * 2 + lc) : (4 + kgs * 16 + (p - 1) * 2 + lc);
    cp16(wpnb + (size_t)(c32 * 8 + frag) * 512 + lane * 8,
         dst + ((kgs * 2 + lc) * 8 + frag) * 512, lane);
  }
}

__global__ void __launch_bounds__(512, 2) lstm_coop(
    const float* __restrict__ hist, const float* __restrict__ blstm,
    const unsigned short* __restrict__ wp,
    unsigned short* __restrict__ hp_hi, unsigned short* __restrict__ hp_lo,
    float* __restrict__ cfin, unsigned* __restrict__ flags){
  __shared__ __align__(16) unsigned short stage[2 * SBUF];  // 64 KiB double buffer
  __shared__ __align__(16) float red[8192];                 // 32 KiB K-partial exchange

  int b = blockIdx.x;
  int xcd = b & 7, jj = b >> 3;
  int nb = xcd * 8 + (jj & 7);          // XCD-local nb for L2 locality
  int mb = jj >> 3;
  int tid = threadIdx.x;
  int w = tid >> 6, lane = tid & 63;
  int kg = w >> 2, wr = w & 3;
  int u = lane & 15, q = lane >> 4;
  int rbase = mb * 128 + wr * 32;

  const unsigned short* wp_nb = wp + (size_t)nb * WP_NB;

  float bias_v[4];
#pragma unroll
  for (int nt = 0; nt < 4; nt++) bias_v[nt] = blstm[nt * H_ + nb * 16 + u];

  int rowA0 = rbase + u;                       // A-fragment rows (m=0 tile)
  int aoff0 = rowA0 * 32 + q * 8;              // elems; + hseg*16384 (+512 for m=1)
  const float* xb0 = hist + (size_t)rowA0 * (T_ * F_) + q * 8;

  // h write offsets (C/D layout: unit = lane&15, row = q*4 + r (+16m))
  int hsegw = nb >> 1;
  int kin = (nb & 1) * 16 + u;
  int howbase = hsegw * 16384 + (rbase + q * 4) * 32 + kin;

  float cst[2][4];
#pragma unroll
  for (int m = 0; m < 2; m++)
#pragma unroll
    for (int r = 0; r < 4; r++) cst[m][r] = 0.f;

  // prologue: stage phase 0 of t=0
  stage_phase(wp_nb, stage, 0, w, lane);
  int cb = 0;

#pragma unroll 1
  for (int t = 0; t < T_; ++t){
    int bufr = t & 1, bufw = bufr ^ 1;
    const unsigned short* rh = hp_hi + bufr * HPBUF;
    const unsigned short* rl = hp_lo + bufr * HPBUF;

    float4v acc[2][4];
#pragma unroll
    for (int m = 0; m < 2; m++)
#pragma unroll
      for (int nt = 0; nt < 4; nt++) acc[m][nt] = (float4v){0.f, 0.f, 0.f, 0.f};

#pragma unroll 1
    for (int p = 0; p < 9; ++p){
      __syncthreads();                       // staged data of phase p ready (vmcnt drained)
      // prefetch next phase (p==8 prefetches next step's phase 0: W only, no dependency)
      stage_phase(wp_nb, stage + (cb ^ 1) * SBUF, (p < 8) ? p + 1 : 0, w, lane);

      // arrive-early/wait-late grid barrier: phase 0 (x cols) needs no h(t-1);
      // wave 0 polls while the other 7 waves compute phase 0.
      if (p == 0 && t && w == 0){
        const unsigned* f = flags + t * NBLK + lane * 4;
        int ok;
        do {
          ok = 1;
#pragma unroll
          for (int i = 0; i < 4; i++)
            ok &= (__hip_atomic_load(&f[i], __ATOMIC_RELAXED, __HIP_MEMORY_SCOPE_AGENT) != 0u);
          if (!ok) __builtin_amdgcn_s_sleep(2);
        } while (!__all(ok));
        __builtin_amdgcn_fence(__ATOMIC_ACQUIRE, "agent");   // L2 inv before any h(t-1) read
      }

      const unsigned short* sb = stage + cb * SBUF + kg * 8192;
      int c0 = (p == 0) ? kg * 2 : 4 + kg * 16 + (p - 1) * 2;
#pragma unroll
      for (int s = 0; s < 2; s++){
        int c32 = c0 + s;
        short8 ah[2], al[2];
        if (c32 < 4){                         // x part: split fp32 history on the fly
#pragma unroll
          for (int m = 0; m < 2; m++){
            const float* px = xb0 + (size_t)m * 16 * (T_ * F_) + t * F_ + c32 * 32;
            float4v v0 = *(const float4v*)px;
            float4v v1 = *(const float4v*)(px + 4);
            short8 hi8, lo8;
#pragma unroll
            for (int j = 0; j < 8; j++){
              float x = (j < 4) ? v0[j] : v1[j - 4];
              unsigned short hb = f2bf(x);
              hi8[j] = (short)hb;
              lo8[j] = (short)f2bf(x - bf2f(hb));
            }
            ah[m] = hi8; al[m] = lo8;
          }
        } else {
          int off = (c32 - 4) * 16384 + aoff0;
          ah[0] = *(const short8*)(rh + off);
          ah[1] = *(const short8*)(rh + off + 512);
          al[0] = *(const short8*)(rl + off);
          al[1] = *(const short8*)(rl + off + 512);
        }
        const unsigned short* fb = sb + s * 4096 + lane * 8;
        short8 bh[4], bl[4];
#pragma unroll
        for (int nt = 0; nt < 4; nt++){
          bh[nt] = *(const short8*)(fb + nt * 512);
          bl[nt] = *(const short8*)(fb + (4 + nt) * 512);
        }
#pragma unroll
        for (int nt = 0; nt < 4; nt++){
          acc[0][nt] = MFMA(ah[0], bh[nt], acc[0][nt]);
          acc[1][nt] = MFMA(ah[1], bh[nt], acc[1][nt]);
        }
#pragma unroll
        for (int nt = 0; nt < 4; nt++){
          acc[0][nt] = MFMA(ah[0], bl[nt], acc[0][nt]);
          acc[1][nt] = MFMA(ah[1], bl[nt], acc[1][nt]);
        }
#pragma unroll
        for (int nt = 0; nt < 4; nt++){
          acc[0][nt] = MFMA(al[0], bh[nt], acc[0][nt]);
          acc[1][nt] = MFMA(al[1], bh[nt], acc[1][nt]);
        }
      }
      cb ^= 1;
    }

    // ---- cross-K reduction: kg1 partials -> LDS, kg0 adds ----
    __syncthreads();                           // all compute done; red region free
    if (kg == 1){
#pragma unroll
      for (int m = 0; m < 2; m++)
#pragma unroll
        for (int nt = 0; nt < 4; nt++)
          *(float4v*)&red[(((m * 4 + nt) * 256) + wr * 64 + lane) * 4] = acc[m][nt];
    }
    __syncthreads();

    // gate update by kg0 waves (all lane-local: ntile == gate)
    if (kg == 0){
      unsigned short* wh = hp_hi + bufw * HPBUF;
      unsigned short* wl2 = hp_lo + bufw * HPBUF;
#pragma unroll
      for (int m = 0; m < 2; m++){
#pragma unroll
        for (int nt = 0; nt < 4; nt++)
          acc[m][nt] += *(const float4v*)&red[(((m * 4 + nt) * 256) + wr * 64 + lane) * 4];
#pragma unroll
        for (int r = 0; r < 4; r++){
          float zi = acc[m][0][r] + bias_v[0];
          float zj = acc[m][1][r] + bias_v[1];
          float zf = acc[m][2][r] + bias_v[2];
          float zo = acc[m][3][r] + bias_v[3];
          float co = cst[m][r];
          float cn = sigf(zf + 1.f) * co + sigf(zi) * tanh_f(zj);
          float hn = sigf(zo) * tanh_f(cn);
          cst[m][r] = cn;
          int off = howbase + (16 * m + r) * 32;
          unsigned short hb = f2bf(hn);
          wh[off] = hb;
          wl2[off] = f2bf(hn - bf2f(hb));
          if (t == T_ - 1){
            int row = rbase + 16 * m + q * 4 + r;
            cfin[(size_t)row * H_ + nb * 16 + u] = cn;
          }
        }
      }
    }
    __syncthreads();                           // drains vmcnt: h stores complete at L2
    if (tid == 0 && t + 1 < T_){
      __builtin_amdgcn_fence(__ATOMIC_RELEASE, "agent");   // push h to coherence point
      __hip_atomic_store(&flags[(t + 1) * NBLK + b], 1u, __ATOMIC_RELAXED,
                         __HIP_MEMORY_SCOPE_AGENT);        // arrive for step t+1
    }
  }
}

// ---------------- head ----------------
__global__ void __launch_bounds__(256) build_feat(const float* __restrict__ head,
    const float* __restrict__ cfin, const unsigned short* __restrict__ hh,
    const unsigned short* __restrict__ hl, float* __restrict__ feat){
  int row = blockIdx.x;
  for (int kp = threadIdx.x; kp < 2080; kp += 256){
    float v;
    if (kp < 2) v = head[row * 3 + 1 + kp];
    else if (kp < 1026) v = cfin[(size_t)row * H_ + (kp - 2)];
    else if (kp < 2050){
      int n = kp - 1026;
      int off = (n >> 5) * 16384 + row * 32 + ((n & 31) >> 3) * 8 + (n & 7);
      v = bf2f(hh[off]) + bf2f(hl[off]);
    } else v = 0.f;
    feat[(size_t)row * 2080 + kp] = v;
  }
}

__global__ void __launch_bounds__(256) mlp_head(const float* __restrict__ feat,
    const float* __restrict__ W3, const float* __restrict__ b3,
    const float* __restrict__ W4, const float* __restrict__ b4,
    const float* __restrict__ W5, const float* __restrict__ b5,
    const float* __restrict__ W6, const float* __restrict__ b6,
    float* __restrict__ G){
  __shared__ float ftile[64][33];
  int bid = blockIdx.x;
  int mb = bid >> 5, nbk = bid & 31;
  int tid = threadIdx.x;
  int tr = tid >> 4, tc = tid & 15;
  int mat = nbk >> 3;
  const float* Wm = (mat == 0) ? W3 : (mat == 1) ? W4 : (mat == 2) ? W5 : W6;
  const float* bm = (mat == 0) ? b3 : (mat == 1) ? b4 : (mat == 2) ? b5 : b6;
  int lc = (nbk & 7) * 64 + tc * 4;
  int r0 = mb * 64;
  float racc[4][4] = {};
  for (int k0 = 0; k0 < 2080; k0 += 32){
    int rr = tid >> 3, cc = (tid & 7) * 4;
    float4v v0 = *(const float4v*)&feat[(size_t)(r0 + rr) * 2080 + k0 + cc];
    float4v v1 = *(const float4v*)&feat[(size_t)(r0 + rr + 32) * 2080 + k0 + cc];
#pragma unroll
    for (int i = 0; i < 4; i++){ ftile[rr][cc + i] = v0[i]; ftile[rr + 32][cc + i] = v1[i]; }
    __syncthreads();
#pragma unroll 4
    for (int kk = 0; kk < 32; kk++){
      int k = k0 + kk;
      float4v bv = (float4v){0.f, 0.f, 0.f, 0.f};
      if (k < 2050) bv = *(const float4v*)&Wm[(size_t)k * 512 + lc];
      float a0 = ftile[tr * 4 + 0][kk];
      float a1 = ftile[tr * 4 + 1][kk];
      float a2 = ftile[tr * 4 + 2][kk];
      float a3 = ftile[tr * 4 + 3][kk];
#pragma unroll
      for (int j = 0; j < 4; j++){
        racc[0][j] += a0 * bv[j]; racc[1][j] += a1 * bv[j];
        racc[2][j] += a2 * bv[j]; racc[3][j] += a3 * bv[j];
      }
    }
    __syncthreads();
  }
#pragma unroll
  for (int i = 0; i < 4; i++){
    float4v v;
#pragma unroll
    for (int j = 0; j < 4; j++){
      float x = racc[i][j] + bm[lc + j];
      v[j] = fmaxf(x, 0.f);
    }
    *(float4v*)&G[(size_t)(r0 + tr * 4 + i) * 2048 + nbk * 64 + tc * 4] = v;
  }
}

__global__ void __launch_bounds__(256) final_q(const float* __restrict__ G,
    const float* __restrict__ head, const float* __restrict__ tq, const int* __restrict__ act,
    const float* __restrict__ Wsv, const float* __restrict__ bsv,
    const float* __restrict__ Wbv, const float* __restrict__ bbv,
    const float* __restrict__ Wsh, const float* __restrict__ bsh,
    const float* __restrict__ Wbh, const float* __restrict__ bbh,
    float* __restrict__ out){
  int row = blockIdx.x, tid = threadIdx.x;
  const float* g = G + (size_t)row * 2048;
  float s0=0,s1=0,s2=0,s3=0,s4=0,s5=0;
  for (int k = tid; k < 512; k += 256){
    float vlp = g[k], qlp = g[512 + k], vle = g[1024 + k], qle = g[1536 + k];
    s0 += vlp * Wsv[k];
    s1 += qlp * Wsh[2 * k];  s2 += qlp * Wsh[2 * k + 1];
    s3 += vle * Wbv[k];
    s4 += qle * Wbh[2 * k];  s5 += qle * Wbh[2 * k + 1];
  }
#pragma unroll
  for (int off = 32; off; off >>= 1){
    s0 += __shfl_down(s0, off); s1 += __shfl_down(s1, off); s2 += __shfl_down(s2, off);
    s3 += __shfl_down(s3, off); s4 += __shfl_down(s4, off); s5 += __shfl_down(s5, off);
  }
  __shared__ float red[4][6];
  int w = tid >> 6, lane = tid & 63;
  if (lane == 0){ red[w][0]=s0; red[w][1]=s1; red[w][2]=s2; red[w][3]=s3; red[w][4]=s4; red[w][5]=s5; }
  __syncthreads();
  if (tid == 0){
    float r[6];
#pragma unroll
    for (int i = 0; i < 6; i++) r[i] = red[0][i] + red[1][i] + red[2][i] + red[3][i];
    float pa0 = r[1] + bsh[0], pa1 = r[2] + bsh[1];
    float pv  = r[0] + bsv[0];
    float pm  = 0.5f * (pa0 + pa1);
    float pQ0 = pa0 - pm + pv, pQ1 = pa1 - pm + pv;
    float ea0 = r[4] + bbh[0], ea1 = r[5] + bbh[1];
    float ev  = r[3] + bbv[0];
    float em  = 0.5f * (ea0 + ea1);
    float eQ0 = ea0 - em + ev, eQ1 = ea1 - em + ev;
    bool isp = (head[row * 3] != 0.f);
    float Q0 = isp ? pQ0 : eQ0;
    float Q1 = isp ? eQ1 : pQ1;   // mask col1 = (1-is_pos)!=0
    float gr = (Q1 > Q0) ? 1.f : 0.f;
    int a = act[row];
    float iv = (a == 0) ? Q0 : Q1;
    float d = tq[row] - iv;
    atomicAdd(out, d * d * (1.f / 512.f));
    out[1 + 2 * row] = Q0;
    out[2 + 2 * row] = Q1;
    out[1025 + row] = gr;
  }
}

// ---------------- launch ----------------
extern "C" void kernel_launch(void* const* d_in, const int* in_sizes, int n_in,
                              void* d_out, int out_size, void* d_ws, size_t ws_size,
                              hipStream_t stream){
  const float* hist = (const float*)d_in[0];
  const float* head = (const float*)d_in[1];
  const float* tq   = (const float*)d_in[2];
  const int*   act  = (const int*)d_in[3];
  const float* Wl   = (const float*)d_in[4];
  const float* bl   = (const float*)d_in[5];
  const float* W3 = (const float*)d_in[6];  const float* b3 = (const float*)d_in[7];
  const float* W4 = (const float*)d_in[8];  const float* b4 = (const float*)d_in[9];
  const float* W5 = (const float*)d_in[10]; const float* b5 = (const float*)d_in[11];
  const float* W6 = (const float*)d_in[12]; const float* b6 = (const float*)d_in[13];
  const float* Wsv = (const float*)d_in[14]; const float* bsv = (const float*)d_in[15];
  const float* Wbv = (const float*)d_in[16]; const float* bbv = (const float*)d_in[17];
  const float* Wsh = (const float*)d_in[18]; const float* bsh = (const float*)d_in[19];
  const float* Wbh = (const float*)d_in[20]; const float* bbh = (const float*)d_in[21];
  float* out = (float*)d_out;

  char* ws = (char*)d_ws;
  unsigned* flags      = (unsigned*)ws;                       // 256*256*4 = 262144
  unsigned short* hp_hi = (unsigned short*)(ws + 262144);      // 2 MiB
  unsigned short* hp_lo = (unsigned short*)(ws + 2359296);     // 2 MiB
  unsigned short* wp    = (unsigned short*)(ws + 4456448);     // 18.87 MB
  float* cfin = (float*)(ws + 23330816);                       // 2 MiB
  float* feat = (float*)(ws + 25427968);                       // 4.26 MB
  float* G    = (float*)(ws + 29687808);                       // 4.19 MB -> total ~33.9 MB

  // zero barrier flags + both h double-buffers (h(-1) = 0)
  hipMemsetAsync(ws, 0, 4456448, stream);
  hipMemsetAsync(d_out, 0, sizeof(float), stream);             // loss accumulator

  pack_w<<<dim3(64 * 36), dim3(256), 0, stream>>>(Wl, wp);

  void* args[] = {(void*)&hist, (void*)&bl, (void*)&wp, (void*)&hp_hi,
                  (void*)&hp_lo, (void*)&cfin, (void*)&flags};
  hipLaunchCooperativeKernel((void*)lstm_coop, dim3(NBLK), dim3(512), args, 0, stream);

  build_feat<<<dim3(512), dim3(256), 0, stream>>>(head, cfin, hp_hi, hp_lo, feat);
  mlp_head<<<dim3(256), dim3(256), 0, stream>>>(feat, W3, b3, W4, b4, W5, b5, W6, b6, G);
  final_q<<<dim3(512), dim3(256), 0, stream>>>(G, head, tq, act,
      Wsv, bsv, Wbv, bbv, Wsh, bsh, Wbh, bbh, out);
}

// Round 2
// 6646.969 us; speedup vs baseline: 1.4579x; 1.1188x over previous
//
#include <hip/hip_runtime.h>
#include <hip/hip_bf16.h>

#define B_ 512
#define T_ 256
#define F_ 128
#define H_ 1024
#define KD 1152          // F_ + H_
#define NBLK 256
#define HPBUF 524288     // elems per hpack buffer: 32 hseg * 512 rows * 32
#define WP_NB 147456     // elems per nb slice of packed W: 36 c32 * 8 frags * 512
#define SBUF 16384       // shorts per stage buffer: 2 kg * 2 c32 * 8 frags * 512 (32 KiB)

typedef __attribute__((ext_vector_type(8))) short short8;
typedef __attribute__((ext_vector_type(4))) float float4v;

#define MFMA(a,b,c) __builtin_amdgcn_mfma_f32_16x16x32_bf16(a,b,c,0,0,0)

__device__ __forceinline__ unsigned short f2bf(float x){
  unsigned u = __float_as_uint(x);
  unsigned r = (u + 0x7fffu + ((u >> 16) & 1u)) >> 16;
  return (unsigned short)r;
}
__device__ __forceinline__ float bf2f(unsigned short b){
  return __uint_as_float(((unsigned)b) << 16);
}
__device__ __forceinline__ float sigf(float x){ return 1.f / (1.f + __expf(-x)); }
__device__ __forceinline__ float tanh_f(float x){
  float e = __expf(2.f * x);
  return (e - 1.f) / (e + 1.f);
}

// async global->LDS copy, 16B per lane. lbase must be wave-uniform; HW adds lane*16.
__device__ __forceinline__ void cp16(const unsigned short* g, unsigned short* lbase, int lane){
#if defined(__has_builtin) && __has_builtin(__builtin_amdgcn_global_load_lds)
  __builtin_amdgcn_global_load_lds((const __attribute__((address_space(1))) unsigned int*)g,
                                   (__attribute__((address_space(3))) unsigned int*)lbase, 16, 0, 0);
#else
  *(short8*)(lbase + lane * 8) = *(const short8*)g;
#endif
}

// ---------------- W pre-pack: split hi/lo bf16 and lay out in MFMA B-fragment order -------------
// wp[nb][c32][frag 0..7][lane*8+j], frag 0..3 = hi for ntile(gate) 0..3, 4..7 = lo.
__global__ void __launch_bounds__(256) pack_w(const float* __restrict__ Wl, unsigned short* __restrict__ wp){
  int bid = blockIdx.x;                 // 64*36
  int nb = bid / 36, c32 = bid % 36;
  int tid = threadIdx.x;
  int nt = tid >> 6, lane = tid & 63;
  int u = lane & 15, q = lane >> 4;
  int gcol = nt * H_ + nb * 16 + u;     // ntile == gate
  int k0 = c32 * 32 + q * 8;
  short8 hi, lo;
#pragma unroll
  for (int j = 0; j < 8; j++){
    float x = Wl[(size_t)(k0 + j) * 4096 + gcol];
    unsigned short hb = f2bf(x);
    hi[j] = (short)hb;
    lo[j] = (short)f2bf(x - bf2f(hb));
  }
  size_t base = (size_t)(nb * 36 + c32) * 8;
  *(short8*)&wp[(base + nt) * 512 + lane * 8] = hi;
  *(short8*)&wp[(base + 4 + nt) * 512 + lane * 8] = lo;
}

// ---------------- persistent cooperative LSTM kernel ----------------
// 8 waves: wr = w&3 picks 32-row group, kg = w>>2 picks K-half.
// kg0: c32 {0,1} + h c32 4..19 ; kg1: c32 {2,3} + h c32 20..35.
// Phase p stages/computes 2 c32 per kg (32 KiB per phase, double-buffered).
__device__ __forceinline__ void stage_phase(const unsigned short* __restrict__ wpnb,
                                            unsigned short* dst, int p, int w, int lane){
#pragma unroll
  for (int i = 0; i < 4; i++){
    int idx = w * 4 + i;                 // 32 chunks of 1 KiB
    int kgs = idx >> 4, lc = (idx >> 3) & 1, frag = idx & 7;
    int c32 = (p == 0) ? (kgs * 2 + lc) : (4 + kgs * 16 + (p - 1) * 2 + lc);
    cp16(wpnb + (size_t)(c32 * 8 + frag) * 512 + lane * 8,
         dst + ((kgs * 2 + lc) * 8 + frag) * 512, lane);
  }
}

struct Areg { short8 h[2][2]; short8 l[2][2]; };   // [s][m]

__device__ __forceinline__ void issueA(const unsigned short* __restrict__ rh,
                                       const unsigned short* __restrict__ rl,
                                       int aoff0, int c0, Areg& d){
#pragma unroll
  for (int s = 0; s < 2; s++){
    int off = (c0 + s - 4) * 16384 + aoff0;
    d.h[s][0] = *(const short8*)(rh + off);
    d.h[s][1] = *(const short8*)(rh + off + 512);
    d.l[s][0] = *(const short8*)(rl + off);
    d.l[s][1] = *(const short8*)(rl + off + 512);
  }
}

__device__ __forceinline__ void issueXF(const float* __restrict__ xb0, int tn, int kg,
                                        float4v (&xf)[2][2][2]){
#pragma unroll
  for (int s = 0; s < 2; s++)
#pragma unroll
    for (int m = 0; m < 2; m++){
      const float* px = xb0 + (size_t)m * 16 * (T_ * F_) + tn * F_ + (kg * 2 + s) * 32;
      xf[s][m][0] = *(const float4v*)px;
      xf[s][m][1] = *(const float4v*)(px + 4);
    }
}

__device__ __forceinline__ void loadB(const unsigned short* fb, short8 (&bh)[4], short8 (&bl)[4]){
#pragma unroll
  for (int nt = 0; nt < 4; nt++){
    bh[nt] = *(const short8*)(fb + nt * 512);
    bl[nt] = *(const short8*)(fb + (4 + nt) * 512);
  }
}

__device__ __forceinline__ void mfma3(const short8 (&ah)[2], const short8 (&al)[2],
                                      const short8 (&bh)[4], const short8 (&bl)[4],
                                      float4v (&acc)[2][4]){
#pragma unroll
  for (int nt = 0; nt < 4; nt++){
    acc[0][nt] = MFMA(ah[0], bh[nt], acc[0][nt]);
    acc[1][nt] = MFMA(ah[1], bh[nt], acc[1][nt]);
  }
#pragma unroll
  for (int nt = 0; nt < 4; nt++){
    acc[0][nt] = MFMA(ah[0], bl[nt], acc[0][nt]);
    acc[1][nt] = MFMA(ah[1], bl[nt], acc[1][nt]);
  }
#pragma unroll
  for (int nt = 0; nt < 4; nt++){
    acc[0][nt] = MFMA(al[0], bh[nt], acc[0][nt]);
    acc[1][nt] = MFMA(al[1], bh[nt], acc[1][nt]);
  }
}

__device__ __forceinline__ void computeH(const unsigned short* sbl, const Areg& a, float4v (&acc)[2][4]){
#pragma unroll
  for (int s = 0; s < 2; s++){
    short8 bh[4], bl[4];
    loadB(sbl + s * 4096, bh, bl);
    mfma3(a.h[s], a.l[s], bh, bl, acc);
  }
}

__device__ __forceinline__ void computeX(const float4v (&xf)[2][2][2], const unsigned short* sbl,
                                         float4v (&acc)[2][4]){
#pragma unroll
  for (int s = 0; s < 2; s++){
    short8 ah[2], al[2];
#pragma unroll
    for (int m = 0; m < 2; m++){
      short8 hi8, lo8;
#pragma unroll
      for (int j = 0; j < 8; j++){
        float x = (j < 4) ? xf[s][m][0][j] : xf[s][m][1][j - 4];
        unsigned short hb = f2bf(x);
        hi8[j] = (short)hb;
        lo8[j] = (short)f2bf(x - bf2f(hb));
      }
      ah[m] = hi8; al[m] = lo8;
    }
    short8 bh[4], bl[4];
    loadB(sbl + s * 4096, bh, bl);
    mfma3(ah, al, bh, bl, acc);
  }
}

__global__ void __launch_bounds__(512, 2) lstm_coop(
    const float* __restrict__ hist, const float* __restrict__ blstm,
    const unsigned short* __restrict__ wp,
    unsigned short* __restrict__ hp_hi, unsigned short* __restrict__ hp_lo,
    float* __restrict__ cfin, unsigned* __restrict__ flags){
  __shared__ __align__(16) unsigned short stage[2 * SBUF];  // 64 KiB double buffer
  __shared__ __align__(16) float red[8192];                 // 32 KiB K-partial exchange

  int b = blockIdx.x;
  int xcd = b & 7, jj = b >> 3;
  int nb = xcd * 8 + (jj & 7);          // XCD-local nb for L2 locality
  int mb = jj >> 3;                     // == b >> 6 ; barrier group
  int tid = threadIdx.x;
  int w = tid >> 6, lane = tid & 63;
  int kg = w >> 2, wr = w & 3;
  int u = lane & 15, q = lane >> 4;
  int rbase = mb * 128 + wr * 32;

  const unsigned short* wp_nb = wp + (size_t)nb * WP_NB;

  float bias_v[4];
#pragma unroll
  for (int nt = 0; nt < 4; nt++) bias_v[nt] = blstm[nt * H_ + nb * 16 + u];

  int rowA0 = rbase + u;                       // A-fragment rows (m=0 tile)
  int aoff0 = rowA0 * 32 + q * 8;              // elems; + hseg*16384 (+512 for m=1)
  const float* xb0 = hist + (size_t)rowA0 * (T_ * F_) + q * 8;

  // h write offsets (C/D layout: unit = lane&15, row = q*4 + r (+16m)); this wave stores m = kg
  int hsegw = nb >> 1;
  int kin = (nb & 1) * 16 + u;
  int howm = hsegw * 16384 + (rbase + 16 * kg + q * 4) * 32 + kin;
  int rowc = rbase + 16 * kg + q * 4;

  float cst[4];                                // c-state for this wave's m = kg rows
#pragma unroll
  for (int r = 0; r < 4; r++) cst[r] = 0.f;

  int c0k = 4 + kg * 16;

  // prologue: stage phase 0 of t=0, prefetch x(t=0)
  stage_phase(wp_nb, stage, 0, w, lane);
  Areg A0, A1;
  float4v xf[2][2][2];
  issueXF(xb0, 0, kg, xf);
  int cb = 0;

#pragma unroll 1
  for (int t = 0; t < T_; ++t){
    int bufr = t & 1, bufw = bufr ^ 1;
    const unsigned short* rh = hp_hi + bufr * HPBUF;
    const unsigned short* rl = hp_lo + bufr * HPBUF;

    float4v acc[2][4];
#pragma unroll
    for (int m = 0; m < 2; m++)
#pragma unroll
      for (int nt = 0; nt < 4; nt++) acc[m][nt] = (float4v){0.f, 0.f, 0.f, 0.f};

    // ---- phase 0: x columns (no h dependency); wave0 polls group barrier meanwhile ----
    __syncthreads();                                         // stage(0)+xf drained
    stage_phase(wp_nb, stage + (cb ^ 1) * SBUF, 1, w, lane);
    if (t && w == 0){
      const unsigned* f = flags + t * NBLK + (mb << 6);      // own 64-block group
      int ok;
      do {
        ok = (__hip_atomic_load(&f[lane], __ATOMIC_RELAXED, __HIP_MEMORY_SCOPE_AGENT) != 0u);
        if (__all(ok)) break;
        __builtin_amdgcn_s_sleep(2);
      } while (1);
      __builtin_amdgcn_fence(__ATOMIC_ACQUIRE, "agent");     // L2 inv before any h(t-1) read
    }
    computeX(xf, stage + cb * SBUF + kg * 8192 + lane * 8, acc);
    if (t) __syncthreads();                                  // order all waves after fence
    issueA(rh, rl, aoff0, c0k, A0);                          // prefetch A(1)
    cb ^= 1;

    // ---- phases 1..8: h columns, A prefetched one phase ahead ----
#pragma unroll
    for (int pq = 0; pq < 4; pq++){
      const int p1 = 1 + 2 * pq, p2 = 2 + 2 * pq;
      __syncthreads();                                       // stage(p1)+A(p1) drained
      stage_phase(wp_nb, stage + (cb ^ 1) * SBUF, p1 + 1, w, lane);
      issueA(rh, rl, aoff0, c0k + p1 * 2, A1);               // A(p1+1)
      computeH(stage + cb * SBUF + kg * 8192 + lane * 8, A0, acc);
      cb ^= 1;
      __syncthreads();                                       // stage(p2)+A(p2) drained
      stage_phase(wp_nb, stage + (cb ^ 1) * SBUF, (p2 < 8) ? p2 + 1 : 0, w, lane);
      if (p2 < 8) issueA(rh, rl, aoff0, c0k + p2 * 2, A0);   // A(p2+1)
      else        issueXF(xb0, (t + 1 < T_) ? t + 1 : t, kg, xf);  // x(t+1)
      computeH(stage + cb * SBUF + kg * 8192 + lane * 8, A1, acc);
      cb ^= 1;
    }

    // ---- cross-K exchange: each kg finalizes its own m (= kg) tile ----
    __syncthreads();                           // all compute done; red region free
    if (kg == 0){                              // hand m=1 partial to kg1
#pragma unroll
      for (int nt = 0; nt < 4; nt++)
        *(float4v*)&red[4096 + ((wr * 4 + nt) * 64 + lane) * 4] = acc[1][nt];
    } else {                                   // hand m=0 partial to kg0
#pragma unroll
      for (int nt = 0; nt < 4; nt++)
        *(float4v*)&red[((wr * 4 + nt) * 64 + lane) * 4] = acc[0][nt];
    }
    __syncthreads();

    unsigned short* wh = hp_hi + bufw * HPBUF;
    unsigned short* wl2 = hp_lo + bufw * HPBUF;
    {
      float4v am[4];
      if (kg == 0){
#pragma unroll
        for (int nt = 0; nt < 4; nt++)
          am[nt] = acc[0][nt] + *(const float4v*)&red[((wr * 4 + nt) * 64 + lane) * 4];
      } else {
#pragma unroll
        for (int nt = 0; nt < 4; nt++)
          am[nt] = acc[1][nt] + *(const float4v*)&red[4096 + ((wr * 4 + nt) * 64 + lane) * 4];
      }
#pragma unroll
      for (int r = 0; r < 4; r++){
        float zi = am[0][r] + bias_v[0];
        float zj = am[1][r] + bias_v[1];
        float zf = am[2][r] + bias_v[2];
        float zo = am[3][r] + bias_v[3];
        float co = cst[r];
        float cn = sigf(zf + 1.f) * co + sigf(zi) * tanh_f(zj);
        float hn = sigf(zo) * tanh_f(cn);
        cst[r] = cn;
        int off = howm + r * 32;
        unsigned short hb = f2bf(hn);
        wh[off] = hb;
        wl2[off] = f2bf(hn - bf2f(hb));
        if (t == T_ - 1)
          cfin[(size_t)(rowc + r) * H_ + nb * 16 + u] = cn;
      }
    }
    __syncthreads();                           // drains vmcnt: h stores complete at L2
    if (tid == 0 && t + 1 < T_){
      __builtin_amdgcn_fence(__ATOMIC_RELEASE, "agent");   // push h to coherence point
      __hip_atomic_store(&flags[(t + 1) * NBLK + b], 1u, __ATOMIC_RELAXED,
                         __HIP_MEMORY_SCOPE_AGENT);        // arrive for step t+1
    }
  }
}

// ---------------- head ----------------
__global__ void __launch_bounds__(256) build_feat(const float* __restrict__ head,
    const float* __restrict__ cfin, const unsigned short* __restrict__ hh,
    const unsigned short* __restrict__ hl, float* __restrict__ feat){
  int row = blockIdx.x;
  for (int kp = threadIdx.x; kp < 2080; kp += 256){
    float v;
    if (kp < 2) v = head[row * 3 + 1 + kp];
    else if (kp < 1026) v = cfin[(size_t)row * H_ + (kp - 2)];
    else if (kp < 2050){
      int n = kp - 1026;
      int off = (n >> 5) * 16384 + row * 32 + ((n & 31) >> 3) * 8 + (n & 7);
      v = bf2f(hh[off]) + bf2f(hl[off]);
    } else v = 0.f;
    feat[(size_t)row * 2080 + kp] = v;
  }
}

__global__ void __launch_bounds__(256) mlp_head(const float* __restrict__ feat,
    const float* __restrict__ W3, const float* __restrict__ b3,
    const float* __restrict__ W4, const float* __restrict__ b4,
    const float* __restrict__ W5, const float* __restrict__ b5,
    const float* __restrict__ W6, const float* __restrict__ b6,
    float* __restrict__ G){
  __shared__ float ftile[64][33];
  int bid = blockIdx.x;
  int mb = bid >> 5, nbk = bid & 31;
  int tid = threadIdx.x;
  int tr = tid >> 4, tc = tid & 15;
  int mat = nbk >> 3;
  const float* Wm = (mat == 0) ? W3 : (mat == 1) ? W4 : (mat == 2) ? W5 : W6;
  const float* bm = (mat == 0) ? b3 : (mat == 1) ? b4 : (mat == 2) ? b5 : b6;
  int lc = (nbk & 7) * 64 + tc * 4;
  int r0 = mb * 64;
  float racc[4][4] = {};
  for (int k0 = 0; k0 < 2080; k0 += 32){
    int rr = tid >> 3, cc = (tid & 7) * 4;
    float4v v0 = *(const float4v*)&feat[(size_t)(r0 + rr) * 2080 + k0 + cc];
    float4v v1 = *(const float4v*)&feat[(size_t)(r0 + rr + 32) * 2080 + k0 + cc];
#pragma unroll
    for (int i = 0; i < 4; i++){ ftile[rr][cc + i] = v0[i]; ftile[rr + 32][cc + i] = v1[i]; }
    __syncthreads();
#pragma unroll 4
    for (int kk = 0; kk < 32; kk++){
      int k = k0 + kk;
      float4v bv = (float4v){0.f, 0.f, 0.f, 0.f};
      if (k < 2050) bv = *(const float4v*)&Wm[(size_t)k * 512 + lc];
      float a0 = ftile[tr * 4 + 0][kk];
      float a1 = ftile[tr * 4 + 1][kk];
      float a2 = ftile[tr * 4 + 2][kk];
      float a3 = ftile[tr * 4 + 3][kk];
#pragma unroll
      for (int j = 0; j < 4; j++){
        racc[0][j] += a0 * bv[j]; racc[1][j] += a1 * bv[j];
        racc[2][j] += a2 * bv[j]; racc[3][j] += a3 * bv[j];
      }
    }
    __syncthreads();
  }
#pragma unroll
  for (int i = 0; i < 4; i++){
    float4v v;
#pragma unroll
    for (int j = 0; j < 4; j++){
      float x = racc[i][j] + bm[lc + j];
      v[j] = fmaxf(x, 0.f);
    }
    *(float4v*)&G[(size_t)(r0 + tr * 4 + i) * 2048 + nbk * 64 + tc * 4] = v;
  }
}

__global__ void __launch_bounds__(256) final_q(const float* __restrict__ G,
    const float* __restrict__ head, const float* __restrict__ tq, const int* __restrict__ act,
    const float* __restrict__ Wsv, const float* __restrict__ bsv,
    const float* __restrict__ Wbv, const float* __restrict__ bbv,
    const float* __restrict__ Wsh, const float* __restrict__ bsh,
    const float* __restrict__ Wbh, const float* __restrict__ bbh,
    float* __restrict__ out){
  int row = blockIdx.x, tid = threadIdx.x;
  const float* g = G + (size_t)row * 2048;
  float s0=0,s1=0,s2=0,s3=0,s4=0,s5=0;
  for (int k = tid; k < 512; k += 256){
    float vlp = g[k], qlp = g[512 + k], vle = g[1024 + k], qle = g[1536 + k];
    s0 += vlp * Wsv[k];
    s1 += qlp * Wsh[2 * k];  s2 += qlp * Wsh[2 * k + 1];
    s3 += vle * Wbv[k];
    s4 += qle * Wbh[2 * k];  s5 += qle * Wbh[2 * k + 1];
  }
#pragma unroll
  for (int off = 32; off; off >>= 1){
    s0 += __shfl_down(s0, off); s1 += __shfl_down(s1, off); s2 += __shfl_down(s2, off);
    s3 += __shfl_down(s3, off); s4 += __shfl_down(s4, off); s5 += __shfl_down(s5, off);
  }
  __shared__ float red[4][6];
  int w = tid >> 6, lane = tid & 63;
  if (lane == 0){ red[w][0]=s0; red[w][1]=s1; red[w][2]=s2; red[w][3]=s3; red[w][4]=s4; red[w][5]=s5; }
  __syncthreads();
  if (tid == 0){
    float r[6];
#pragma unroll
    for (int i = 0; i < 6; i++) r[i] = red[0][i] + red[1][i] + red[2][i] + red[3][i];
    float pa0 = r[1] + bsh[0], pa1 = r[2] + bsh[1];
    float pv  = r[0] + bsv[0];
    float pm  = 0.5f * (pa0 + pa1);
    float pQ0 = pa0 - pm + pv, pQ1 = pa1 - pm + pv;
    float ea0 = r[4] + bbh[0], ea1 = r[5] + bbh[1];
    float ev  = r[3] + bbv[0];
    float em  = 0.5f * (ea0 + ea1);
    float eQ0 = ea0 - em + ev, eQ1 = ea1 - em + ev;
    bool isp = (head[row * 3] != 0.f);
    float Q0 = isp ? pQ0 : eQ0;
    float Q1 = isp ? eQ1 : pQ1;   // mask col1 = (1-is_pos)!=0
    float gr = (Q1 > Q0) ? 1.f : 0.f;
    int a = act[row];
    float iv = (a == 0) ? Q0 : Q1;
    float d = tq[row] - iv;
    atomicAdd(out, d * d * (1.f / 512.f));
    out[1 + 2 * row] = Q0;
    out[2 + 2 * row] = Q1;
    out[1025 + row] = gr;
  }
}

// ---------------- launch ----------------
extern "C" void kernel_launch(void* const* d_in, const int* in_sizes, int n_in,
                              void* d_out, int out_size, void* d_ws, size_t ws_size,
                              hipStream_t stream){
  const float* hist = (const float*)d_in[0];
  const float* head = (const float*)d_in[1];
  const float* tq   = (const float*)d_in[2];
  const int*   act  = (const int*)d_in[3];
  const float* Wl   = (const float*)d_in[4];
  const float* bl   = (const float*)d_in[5];
  const float* W3 = (const float*)d_in[6];  const float* b3 = (const float*)d_in[7];
  const float* W4 = (const float*)d_in[8];  const float* b4 = (const float*)d_in[9];
  const float* W5 = (const float*)d_in[10]; const float* b5 = (const float*)d_in[11];
  const float* W6 = (const float*)d_in[12]; const float* b6 = (const float*)d_in[13];
  const float* Wsv = (const float*)d_in[14]; const float* bsv = (const float*)d_in[15];
  const float* Wbv = (const float*)d_in[16]; const float* bbv = (const float*)d_in[17];
  const float* Wsh = (const float*)d_in[18]; const float* bsh = (const float*)d_in[19];
  const float* Wbh = (const float*)d_in[20]; const float* bbh = (const float*)d_in[21];
  float* out = (float*)d_out;

  char* ws = (char*)d_ws;
  unsigned* flags      = (unsigned*)ws;                       // 256*256*4 = 262144
  unsigned short* hp_hi = (unsigned short*)(ws + 262144);      // 2 MiB
  unsigned short* hp_lo = (unsigned short*)(ws + 2359296);     // 2 MiB
  unsigned short* wp    = (unsigned short*)(ws + 4456448);     // 18.87 MB
  float* cfin = (float*)(ws + 23330816);                       // 2 MiB
  float* feat = (float*)(ws + 25427968);                       // 4.26 MB
  float* G    = (float*)(ws + 29687808);                       // 4.19 MB -> total ~33.9 MB

  // zero barrier flags + both h double-buffers (h(-1) = 0)
  hipMemsetAsync(ws, 0, 4456448, stream);
  hipMemsetAsync(d_out, 0, sizeof(float), stream);             // loss accumulator

  pack_w<<<dim3(64 * 36), dim3(256), 0, stream>>>(Wl, wp);

  void* args[] = {(void*)&hist, (void*)&bl, (void*)&wp, (void*)&hp_hi,
                  (void*)&hp_lo, (void*)&cfin, (void*)&flags};
  hipLaunchCooperativeKernel((void*)lstm_coop, dim3(NBLK), dim3(512), args, 0, stream);

  build_feat<<<dim3(512), dim3(256), 0, stream>>>(head, cfin, hp_hi, hp_lo, feat);
  mlp_head<<<dim3(256), dim3(256), 0, stream>>>(feat, W3, b3, W4, b4, W5, b5, W6, b6, G);
  final_q<<<dim3(512), dim3(256), 0, stream>>>(G, head, tq, act,
      Wsv, bsv, Wbv, bbv, Wsh, bsh, Wbh, bbh, out);
}